// Round 10
// baseline (212.723 us; speedup 1.0000x reference)
//
#include <hip/hip_runtime.h>

#define NSH 512    // NUM_SHARDS
#define NC  256    // NUM_CLUSTERS
#define NI  1024   // INPUT_SIZE
#define NO  1024   // OUTPUT_SIZE
#define NB  1024   // BATCH
#define NMAX 8     // samples per pass per shard
#define UF  4      // float4 loads in flight per thread (k-loops pinned unroll 1)

// ---------------- Kernel 1: group samples by shard (counting sort) ----------
__global__ __launch_bounds__(512) void group_kernel(const int* __restrict__ shard,
                                                    int* __restrict__ order,
                                                    int* __restrict__ base,
                                                    int* __restrict__ cnt) {
    __shared__ int h[NSH];
    __shared__ int woff[8];
    __shared__ int cur[NSH];
    const int tid  = threadIdx.x;      // 512 threads == NSH
    const int lane = tid & 63;
    const int w8   = tid >> 6;
    h[tid] = 0;
    __syncthreads();
    for (int i = tid; i < NB; i += 512) atomicAdd(&h[shard[i]], 1);
    __syncthreads();
    const int v = h[tid];
    int inc = v;                        // inclusive scan within wave
    #pragma unroll
    for (int off = 1; off < 64; off <<= 1) {
        int t = __shfl_up(inc, off, 64);
        if (lane >= off) inc += t;
    }
    if (lane == 63) woff[w8] = inc;
    __syncthreads();
    if (tid == 0) {
        int a = 0;
        #pragma unroll
        for (int i = 0; i < 8; ++i) { int t = woff[i]; woff[i] = a; a += t; }
    }
    __syncthreads();
    const int b0 = woff[w8] + inc - v;  // exclusive prefix
    base[tid] = b0;
    cnt[tid]  = v;
    cur[tid]  = b0;
    __syncthreads();
    for (int i = tid; i < NB; i += 512) {
        int pos = atomicAdd(&cur[shard[i]], 1);
        order[pos] = i;
    }
}

// ---------------- Kernel 2: one block per shard, full fused pipeline --------
// LDS trimmed to ~41 KB (keys staged in 2 halves) so 3 blocks/CU fit.
// __launch_bounds__(512, 3): empirically (R8: (512,4) -> VGPR cap 64) arg2
// acts as blocks/CU -> 3 blocks * 8 waves = 24 waves/CU, VGPR cap ~85.
// UF=4 keeps acc[8]+wv[4]+addr ~70 VGPR (no spill). TLP (24 waves) hides
// latency; depth-4 per wave is secondary.
__global__ __launch_bounds__(512, 3) void mega_kernel(
        const int*   __restrict__ order,
        const int*   __restrict__ base,
        const int*   __restrict__ cnt,
        const float* __restrict__ key,
        const float* __restrict__ wgt,
        const float* __restrict__ lat,
        const float* __restrict__ bias,
        float*       __restrict__ outq,
        float*       __restrict__ outp) {
    const int s     = blockIdx.x;
    const int n_tot = cnt[s];
    if (n_tot == 0) return;
    const int b0   = base[s];
    const int tid  = threadIdx.x;        // 0..511
    const int w    = tid >> 6;           // wave 0..7
    const int lane = tid & 63;
    const int c4   = lane << 2;          // 4 consecutive elems per lane

    const float* __restrict__ Wp = wgt + (size_t)s * (NI * NC);
    const float* __restrict__ Lp = lat + (size_t)s * (NC * NO);

    __shared__ float key_s[NMAX][NI / 2];  // 16 KB (half of i at a time)
    __shared__ float red[4096];            // 16 KB (shared by phase A and B)
    __shared__ float prob_s[NMAX][NC];     //  8 KB
    __shared__ float bias_s[NC];           //  1 KB
    __shared__ float xm[2][4];
    __shared__ float xs[2][4];
    __shared__ int   samp_s[NMAX];

    if (tid < 64)
        *(float4*)&bias_s[tid << 2] =
            *(const float4*)(bias + (size_t)s * NC + (tid << 2));

    for (int p0 = 0; p0 < n_tot; p0 += NMAX) {
        const int n = min(NMAX, n_tot - p0);
        __syncthreads();                 // buffers reused across passes
        if (tid < n) samp_s[tid] = order[b0 + p0 + tid];
        __syncthreads();

        // ---- phase A: stream W in 2 half-i sweeps; acc persists ----
        float4 acc[NMAX];
        #pragma unroll
        for (int j = 0; j < NMAX; ++j) acc[j] = make_float4(0.f, 0.f, 0.f, 0.f);

        #pragma unroll 1
        for (int hf = 0; hf < 2; ++hf) {
            // stage keys for i in [hf*512, hf*512+512): 1024 float4, 2/thread
            for (int idx = tid; idx < NMAX * 128; idx += 512) {
                const int ns = idx >> 7;      // 128 float4 per half-row
                const int e4 = idx & 127;
                float4 v = make_float4(0.f, 0.f, 0.f, 0.f);
                if (ns < n)
                    v = *(const float4*)(key + (size_t)samp_s[ns] * NI
                                             + (hf << 9) + (e4 << 2));
                *(float4*)&key_s[ns][e4 << 2] = v;
            }
            __syncthreads();

            // wave w: rows il = w + 8k (k=0..63) within half; global i = hf*512+il
            #pragma unroll 1             // keep VGPR lean
            for (int k0 = 0; k0 < 64; k0 += UF) {
                float4 wv[UF];
                #pragma unroll
                for (int u = 0; u < UF; ++u)
                    wv[u] = *(const float4*)(Wp
                            + (size_t)((hf << 9) + w + 8 * (k0 + u)) * NC + c4);
                #pragma unroll
                for (int u = 0; u < UF; ++u) {
                    const int il = w + 8 * (k0 + u);
                    #pragma unroll
                    for (int j = 0; j < NMAX; ++j) {
                        const float k = key_s[j][il];     // LDS broadcast
                        acc[j].x = fmaf(k, wv[u].x, acc[j].x);
                        acc[j].y = fmaf(k, wv[u].y, acc[j].y);
                        acc[j].z = fmaf(k, wv[u].z, acc[j].z);
                        acc[j].w = fmaf(k, wv[u].w, acc[j].w);
                    }
                }
            }
            __syncthreads();             // all waves done with key_s half
        }

        // ---- logits + softmax, 2 samples per round (compile-time r) ----
        const int half = tid >> 8;       // 0/1 = which sample of the round
        const int w3   = w & 3;          // wave index within half
        const int cc   = tid & 255;      // cluster owned in reduce/softmax
        #pragma unroll
        for (int r = 0; r < 4; ++r) {
            __syncthreads();             // red free
            *(float4*)&red[w * 512 + c4]       = acc[2 * r];
            *(float4*)&red[w * 512 + 256 + c4] = acc[2 * r + 1];
            __syncthreads();
            const int j = 2 * r + half;
            float lg = -1e30f;
            if (j < n) {
                lg = bias_s[cc];
                #pragma unroll
                for (int ww = 0; ww < 8; ++ww)
                    lg += red[ww * 512 + half * 256 + cc];
            }
            float m = lg;
            #pragma unroll
            for (int off = 32; off >= 1; off >>= 1)
                m = fmaxf(m, __shfl_xor(m, off, 64));
            if (lane == 0) xm[half][w3] = m;
            __syncthreads();
            m = fmaxf(fmaxf(xm[half][0], xm[half][1]),
                      fmaxf(xm[half][2], xm[half][3]));
            const float e = __expf(lg - m);
            float sm = e;
            #pragma unroll
            for (int off = 32; off >= 1; off >>= 1)
                sm += __shfl_xor(sm, off, 64);
            if (lane == 0) xs[half][w3] = sm;
            __syncthreads();
            sm = xs[half][0] + xs[half][1] + xs[half][2] + xs[half][3];
            const float p = e / sm;
            if (j < n) {
                prob_s[j][cc] = p;
                outq[(size_t)samp_s[j] * NC + cc] = p;
            } else {
                prob_s[j][cc] = 0.f;     // pad rows: keep phase B clean
            }
        }
        __syncthreads();                 // prob_s visible to phase B

        // ---- phase B: stream L; wave w: o-chunk oc = w&3, c-phase cp = w>>2;
        //      c = cp + 2k, k = 0..127 ----
        const int oc = w & 3;
        const int cp = w >> 2;
        const int ob = oc << 8;          // o-chunk base (256 outputs)
        float4 acc2[NMAX];
        #pragma unroll
        for (int j = 0; j < NMAX; ++j) acc2[j] = make_float4(0.f, 0.f, 0.f, 0.f);

        #pragma unroll 1
        for (int k0 = 0; k0 < 128; k0 += UF) {
            float4 lv[UF];
            #pragma unroll
            for (int u = 0; u < UF; ++u) {
                const int c = cp + 2 * (k0 + u);
                lv[u] = *(const float4*)(Lp + (size_t)c * NO + ob + c4);
            }
            #pragma unroll
            for (int u = 0; u < UF; ++u) {
                const int c = cp + 2 * (k0 + u);
                #pragma unroll
                for (int j = 0; j < NMAX; ++j) {
                    const float p = prob_s[j][c];     // LDS broadcast
                    acc2[j].x = fmaf(p, lv[u].x, acc2[j].x);
                    acc2[j].y = fmaf(p, lv[u].y, acc2[j].y);
                    acc2[j].z = fmaf(p, lv[u].z, acc2[j].z);
                    acc2[j].w = fmaf(p, lv[u].w, acc2[j].w);
                }
            }
        }

        // ---- cross-phase reduce + store, 2 samples/round (compile-time r) --
        #pragma unroll
        for (int r = 0; r < 4; ++r) {
            __syncthreads();             // red free
            *(float4*)&red[cp * 2048 + ob + c4]        = acc2[2 * r];
            *(float4*)&red[cp * 2048 + 1024 + ob + c4] = acc2[2 * r + 1];
            __syncthreads();
            #pragma unroll
            for (int q = 0; q < 4; ++q) {
                const int flat = (q << 9) | tid;      // 0..2047
                const int sel  = flat >> 10;          // sample of the round
                const int o    = flat & 1023;
                const int j    = 2 * r + sel;
                if (j < n)
                    outp[(size_t)samp_s[j] * NO + o] =
                        red[sel * 1024 + o] + red[2048 + sel * 1024 + o];
            }
        }
    }
}

// ---------------- launch ----------------------------------------------------
extern "C" void kernel_launch(void* const* d_in, const int* in_sizes, int n_in,
                              void* d_out, int out_size, void* d_ws, size_t ws_size,
                              hipStream_t stream) {
    const int*   shard = (const int*)  d_in[0];
    const float* key   = (const float*)d_in[1];
    const float* lat   = (const float*)d_in[2];
    const float* wgt   = (const float*)d_in[3];
    const float* bias  = (const float*)d_in[4];

    float* outp = (float*)d_out;                       // lat_h [NB][NO]
    float* outq = (float*)d_out + (size_t)NB * NO;     // prob  [NB][NC]

    int* order = (int*)d_ws;          // [NB]
    int* base  = order + NB;          // [NSH]
    int* cnt   = base + NSH;          // [NSH]

    group_kernel<<<1,   512, 0, stream>>>(shard, order, base, cnt);
    mega_kernel <<<NSH, 512, 0, stream>>>(order, base, cnt, key, wgt, lat, bias,
                                          outq, outp);
}

// Round 11
// 195.345 us; speedup vs baseline: 1.0890x; 1.0890x over previous
//
#include <hip/hip_runtime.h>

#define NSH 512    // NUM_SHARDS
#define NC  256    // NUM_CLUSTERS
#define NI  1024   // INPUT_SIZE
#define NO  1024   // OUTPUT_SIZE
#define NB  1024   // BATCH
#define NMAX 8     // samples per pass per shard
#define UF  8      // float4 loads in flight per thread (k-loops pinned unroll 1)

// ---------------- single fused kernel: one block per shard ------------------
// Grouping folded in: each block scans shard[] (4 KB, L3-broadcast) and
// compacts its own sample list (LDS atomic; slot order is output-invariant).
// Phase A: stream W (1 MB); wave w owns CONTIGUOUS rows [w*128, w*128+128)
//          -> each wave is a sequential 128 KB DRAM stream (page locality;
//          R3..R9 used stride-8 row interleave = 1 KB hops 8 KB apart).
// Phase B: stream L (1 MB); c-phase cp owns contiguous c in [cp*128, +128).
// __launch_bounds__(512, 2): 2 blocks/CU -> VGPR cap 128 (R8: (512,4) capped
// VGPR at 64 and force-spilled acc to scratch). All acc loops compile-time.
__global__ __launch_bounds__(512, 2) void mega_kernel(
        const int*   __restrict__ shard,
        const float* __restrict__ key,
        const float* __restrict__ wgt,
        const float* __restrict__ lat,
        const float* __restrict__ bias,
        float*       __restrict__ outq,
        float*       __restrict__ outp) {
    const int s    = blockIdx.x;
    const int tid  = threadIdx.x;        // 0..511
    const int w    = tid >> 6;           // wave 0..7
    const int lane = tid & 63;
    const int c4   = lane << 2;          // 4 consecutive elems per lane

    __shared__ float key_s[NMAX][NI];    // 32 KB
    __shared__ float red[4096];          // 16 KB (shared by phase A and B)
    __shared__ float prob_s[NMAX][NC];   //  8 KB
    __shared__ float bias_s[NC];         //  1 KB
    __shared__ int   samp_all[NB];       //  4 KB (worst case: all in one shard)
    __shared__ float xm[2][4];
    __shared__ float xs[2][4];
    __shared__ int   samp_s[NMAX];
    __shared__ int   cnt_s;

    // ---- in-block grouping: collect this shard's samples ----
    if (tid == 0) cnt_s = 0;
    __syncthreads();
    for (int i = tid; i < NB; i += 512) {
        if (shard[i] == s) {
            int p = atomicAdd(&cnt_s, 1);   // slot order is output-invariant
            samp_all[p] = i;
        }
    }
    __syncthreads();
    const int n_tot = cnt_s;
    if (n_tot == 0) return;

    const float* __restrict__ Wp = wgt + (size_t)s * (NI * NC);
    const float* __restrict__ Lp = lat + (size_t)s * (NC * NO);

    if (tid < 64)
        *(float4*)&bias_s[tid << 2] =
            *(const float4*)(bias + (size_t)s * NC + (tid << 2));

    for (int p0 = 0; p0 < n_tot; p0 += NMAX) {
        const int n = min(NMAX, n_tot - p0);
        __syncthreads();                 // buffers reused across passes
        if (tid < n) samp_s[tid] = samp_all[p0 + tid];
        __syncthreads();

        // ---- stage keys: n samples x 1024 floats (2048 float4, 4/thread) ---
        for (int idx = tid; idx < NMAX * (NI / 4); idx += 512) {
            const int ns = idx >> 8;     // 256 float4 per sample row
            const int e4 = idx & 255;
            float4 v = make_float4(0.f, 0.f, 0.f, 0.f);
            if (ns < n)
                v = *(const float4*)(key + (size_t)samp_s[ns] * NI + (e4 << 2));
            *(float4*)&key_s[ns][e4 << 2] = v;
        }
        __syncthreads();

        // ---- phase A: stream W; wave w owns rows [w*128, w*128+128) --------
        float4 acc[NMAX];
        #pragma unroll
        for (int j = 0; j < NMAX; ++j) acc[j] = make_float4(0.f, 0.f, 0.f, 0.f);

        const int rowA = w << 7;         // wave's first i-row
        #pragma unroll 1                 // keep VGPR lean (R5 lesson)
        for (int k0 = 0; k0 < 128; k0 += UF) {
            float4 wv[UF];
            #pragma unroll
            for (int u = 0; u < UF; ++u)
                wv[u] = *(const float4*)(Wp + (size_t)(rowA + k0 + u) * NC + c4);
            #pragma unroll
            for (int u = 0; u < UF; ++u) {
                const int il = rowA + k0 + u;
                #pragma unroll
                for (int j = 0; j < NMAX; ++j) {
                    const float k = key_s[j][il];     // LDS broadcast
                    acc[j].x = fmaf(k, wv[u].x, acc[j].x);
                    acc[j].y = fmaf(k, wv[u].y, acc[j].y);
                    acc[j].z = fmaf(k, wv[u].z, acc[j].z);
                    acc[j].w = fmaf(k, wv[u].w, acc[j].w);
                }
            }
        }

        // ---- logits + softmax, 2 samples per round (compile-time r) ----
        const int half = tid >> 8;       // 0/1 = which sample of the round
        const int w3   = w & 3;          // wave index within half
        const int cc   = tid & 255;      // cluster owned in reduce/softmax
        #pragma unroll
        for (int r = 0; r < 4; ++r) {
            __syncthreads();             // red free
            *(float4*)&red[w * 512 + c4]       = acc[2 * r];
            *(float4*)&red[w * 512 + 256 + c4] = acc[2 * r + 1];
            __syncthreads();
            const int j = 2 * r + half;
            float lg = -1e30f;
            if (j < n) {
                lg = bias_s[cc];
                #pragma unroll
                for (int ww = 0; ww < 8; ++ww)
                    lg += red[ww * 512 + half * 256 + cc];
            }
            float m = lg;
            #pragma unroll
            for (int off = 32; off >= 1; off >>= 1)
                m = fmaxf(m, __shfl_xor(m, off, 64));
            if (lane == 0) xm[half][w3] = m;
            __syncthreads();
            m = fmaxf(fmaxf(xm[half][0], xm[half][1]),
                      fmaxf(xm[half][2], xm[half][3]));
            const float e = __expf(lg - m);
            float sm = e;
            #pragma unroll
            for (int off = 32; off >= 1; off >>= 1)
                sm += __shfl_xor(sm, off, 64);
            if (lane == 0) xs[half][w3] = sm;
            __syncthreads();
            sm = xs[half][0] + xs[half][1] + xs[half][2] + xs[half][3];
            const float p = e / sm;
            if (j < n) {
                prob_s[j][cc] = p;
                outq[(size_t)samp_s[j] * NC + cc] = p;
            } else {
                prob_s[j][cc] = 0.f;     // pad rows: keep phase B clean
            }
        }
        __syncthreads();                 // prob_s visible to phase B

        // ---- phase B: stream L; wave w: o-chunk oc = w&3, c-phase cp = w>>2;
        //      cp owns contiguous c in [cp*128, cp*128+128) ----
        const int oc = w & 3;
        const int cp = w >> 2;
        const int ob = oc << 8;          // o-chunk base (256 outputs)
        const int rowB = cp << 7;        // c-phase's first c-row
        float4 acc2[NMAX];
        #pragma unroll
        for (int j = 0; j < NMAX; ++j) acc2[j] = make_float4(0.f, 0.f, 0.f, 0.f);

        #pragma unroll 1
        for (int k0 = 0; k0 < 128; k0 += UF) {
            float4 lv[UF];
            #pragma unroll
            for (int u = 0; u < UF; ++u) {
                const int c = rowB + k0 + u;
                lv[u] = *(const float4*)(Lp + (size_t)c * NO + ob + c4);
            }
            #pragma unroll
            for (int u = 0; u < UF; ++u) {
                const int c = rowB + k0 + u;
                #pragma unroll
                for (int j = 0; j < NMAX; ++j) {
                    const float p = prob_s[j][c];     // LDS broadcast
                    acc2[j].x = fmaf(p, lv[u].x, acc2[j].x);
                    acc2[j].y = fmaf(p, lv[u].y, acc2[j].y);
                    acc2[j].z = fmaf(p, lv[u].z, acc2[j].z);
                    acc2[j].w = fmaf(p, lv[u].w, acc2[j].w);
                }
            }
        }

        // ---- cross-phase reduce + store, 2 samples/round (compile-time r) --
        #pragma unroll
        for (int r = 0; r < 4; ++r) {
            __syncthreads();             // red free
            *(float4*)&red[cp * 2048 + ob + c4]        = acc2[2 * r];
            *(float4*)&red[cp * 2048 + 1024 + ob + c4] = acc2[2 * r + 1];
            __syncthreads();
            #pragma unroll
            for (int q = 0; q < 4; ++q) {
                const int flat = (q << 9) | tid;      // 0..2047
                const int sel  = flat >> 10;          // sample of the round
                const int o    = flat & 1023;
                const int j    = 2 * r + sel;
                if (j < n)
                    outp[(size_t)samp_s[j] * NO + o] =
                        red[sel * 1024 + o] + red[2048 + sel * 1024 + o];
            }
        }
    }
}

// ---------------- launch ----------------------------------------------------
extern "C" void kernel_launch(void* const* d_in, const int* in_sizes, int n_in,
                              void* d_out, int out_size, void* d_ws, size_t ws_size,
                              hipStream_t stream) {
    const int*   shard = (const int*)  d_in[0];
    const float* key   = (const float*)d_in[1];
    const float* lat   = (const float*)d_in[2];
    const float* wgt   = (const float*)d_in[3];
    const float* bias  = (const float*)d_in[4];

    float* outp = (float*)d_out;                       // lat_h [NB][NO]
    float* outq = (float*)d_out + (size_t)NB * NO;     // prob  [NB][NC]

    mega_kernel<<<NSH, 512, 0, stream>>>(shard, key, wgt, lat, bias, outq, outp);
}